// Round 5
// baseline (330.189 us; speedup 1.0000x reference)
//
#include <hip/hip_runtime.h>
#include <hip/hip_bf16.h>

// Problem constants: B=4, C=64, F=256, T=256, CH=32
typedef __hip_bfloat16 bf16;
typedef __attribute__((ext_vector_type(8))) short bf16x8;
typedef __attribute__((ext_vector_type(4))) float f32x4;
typedef __attribute__((ext_vector_type(16))) float f32x16;
typedef __attribute__((ext_vector_type(8))) unsigned short u16x8;
typedef __attribute__((ext_vector_type(4))) unsigned int u32x4;
typedef __attribute__((ext_vector_type(2))) unsigned int u32x2;

struct ConvP {
  const float* W; const float* bi; const float* g; const float* be;
  const float* m; const float* v; const float* a;
};

// 1/sqrt(32) * log2(e): folded into Q-channel BN params (leaky ReLU is
// positively homogeneous so scale commutes); attention then uses raw exp2.
#define QS (0.17677669529663687f * 1.4426950408889634f)

// m204-style bijective XCD swizzle for a 1024-block grid on 8 XCDs.
// Used in attn/proj only (conv measured -4% with it in R2).
__device__ __forceinline__ int swz1024(int i) {
  return ((i & 7) << 7) | (i >> 3);
}

__device__ __forceinline__ unsigned short f2bf(float f) {
  __hip_bfloat16 h = __float2bfloat16(f);
  return __builtin_bit_cast(unsigned short, h);
}
__device__ __forceinline__ float fast_exp2(float x) {
#if __has_builtin(__builtin_amdgcn_exp2f)
  return __builtin_amdgcn_exp2f(x);
#else
  return exp2f(x);
#endif
}

// ---------------------------------------------------------------------------
// Kernel A (v10): fused 1x1 conv + BN + LeakyReLU via 16x16x32 MFMA.
// v10 insight: each wave's MFMA output rows t=(wid*4+i)*16+m16 are entirely
// inside the wave's own t-range [wid*64,(wid+1)*64) -> staging is WAVE-
// PRIVATE. So:
//  - per-wave [16][40] staging slabs, emit own 1-KB-dense chunk per i with
//    NO barrier (in-order DS pipe within a wave); stores overlap next i's
//    MFMAs. Staging LDS 40 KB -> 10 KB; total 43.75 KB -> 3 blocks/CU.
//  - barriers 8 -> 3 ({inp->Xb}, {Bf reads done, Xb dead}, {x->Xb done}).
//  - x prefetch split in two 8xfloat4 register batches issued around the
//    two qk passes (Xb dead after the one-time Bf fragment reads), hiding
//    x's HBM latency under MFMA work.
// LDS staging kept as the write-coalescing mechanism (v8 lesson: direct
// 4-B/lane stores inflate WRITE 82->131 MB; L2 does not merge partial
// lines across instructions). Math order identical to v5 -> bit-identical.
// ---------------------------------------------------------------------------
__global__ __launch_bounds__(256, 3) void conv_qkv(
    const float* __restrict__ inp, const float* __restrict__ x,
    ConvP fqk, ConvP fv, ConvP tqk,
    bf16* __restrict__ Qf, bf16* __restrict__ Kf, bf16* __restrict__ Vf,
    bf16* __restrict__ Qt, bf16* __restrict__ Kt)
{
  __shared__ __attribute__((aligned(16))) unsigned short Xb[64 * 260];   // 33.3 KB
  __shared__ __attribute__((aligned(16))) unsigned short Sst[4][2][16 * 40]; // 10 KB
  __shared__ __attribute__((aligned(8)))  float2 Pc[160];                // BN (A,B) per o

  const int tid = threadIdx.x;
  const int b = blockIdx.x >> 8;
  const int f = blockIdx.x & 255;
  const size_t gbase = (size_t)b * 64 * 65536 + f * 256;   // (b, c=0, f, t=0)
  const size_t tbase = (size_t)(b * 256 + f) * 8192;       // output tile base

  const int lane = tid & 63;
  const int wid = tid >> 6;
  const int m16 = lane & 15;
  const int quad = lane >> 4;
  const int r4 = lane >> 2, p4 = lane & 3;

  unsigned short* S0w = &Sst[wid][0][0];
  unsigned short* S1w = &Sst[wid][1][0];

  // ---- BN param table: Pc[o] = (A, B2) with y = conv*A + B2 ----
  if (tid < 160) {
    const ConvP& P = (tid < 64) ? fqk : (tid < 128) ? tqk : fv;
    const int o = (tid < 64) ? tid : (tid < 128) ? tid - 64 : tid - 128;
    float A = P.g[o] * rsqrtf(P.v[o] + 1e-5f);
    float B2 = (P.bi[o] - P.m[o]) * A + P.be[o];
    if (tid < 128 && ((o & 1) == 0)) { A *= QS; B2 *= QS; }  // Q channels
    Pc[tid] = make_float2(A, B2);
  }

  // ---- stage inp tile (fp32 global -> bf16 LDS [c][t], stride 260) ----
  {
    #pragma unroll
    for (int r = 0; r < 16; ++r) {
      const int idx = r * 256 + tid;
      const int c = idx >> 6;
      const int t0 = (idx & 63) * 4;
      const float4 v = *(const float4*)(inp + gbase + (size_t)c * 65536 + t0);
      unsigned lo = (unsigned)f2bf(v.x) | (((unsigned)f2bf(v.y)) << 16);
      unsigned hi = (unsigned)f2bf(v.z) | (((unsigned)f2bf(v.w)) << 16);
      u32x2 pk = {lo, hi};
      *(u32x2*)&Xb[c * 260 + t0] = pk;
    }
  }

  // ---- A-frag: W[o = rowbase+m16][k = ks*32+quad*8+j] (fp32 -> bf16) ----
  auto load_A = [&](const float* __restrict__ W, int rowbase, int ks) {
    const float* p = W + (rowbase + m16) * 64 + ks * 32 + quad * 8;
    const float4 lo = *(const float4*)p;
    const float4 hi = *(const float4*)(p + 4);
    bf16x8 r;
    r[0] = (short)f2bf(lo.x); r[1] = (short)f2bf(lo.y);
    r[2] = (short)f2bf(lo.z); r[3] = (short)f2bf(lo.w);
    r[4] = (short)f2bf(hi.x); r[5] = (short)f2bf(hi.y);
    r[6] = (short)f2bf(hi.z); r[7] = (short)f2bf(hi.w);
    return r;
  };

  // ---- B-frag: X[t = tt*16+m16][k = ks*32+quad*8+j] from LDS ----
  auto load_B = [&](int tt, int ks) {
    const int t = tt * 16 + m16;
    const int i0 = ks * 32 + quad * 8;
    bf16x8 r;
    #pragma unroll
    for (int j = 0; j < 8; ++j) r[j] = (short)Xb[(i0 + j) * 260 + t];
    return r;
  };

  auto leaky = [](float y, float alpha) { return y > 0.f ? y : alpha * y; };

  // ---- qk pass: 64-row matrix, de-interleave even->S0w (Q), odd->S1w (K);
  // per-i wave-private emit (16 rows = 1 KB dense per output, no barrier) ----
  auto qk_pass = [&](const ConvP& P, int pcb, const bf16x8 (&Bf)[4][2],
                     bf16* __restrict__ Qd, bf16* __restrict__ Kd) {
    bf16x8 A[4][2];
    #pragma unroll
    for (int ot = 0; ot < 4; ++ot)
      #pragma unroll
      for (int ks = 0; ks < 2; ++ks) A[ot][ks] = load_A(P.W, ot * 16, ks);
    float pA[4][4], pB[4][4];
    #pragma unroll
    for (int ot = 0; ot < 4; ++ot)
      #pragma unroll
      for (int r = 0; r < 4; ++r) {
        const float2 pp = Pc[pcb + ot * 16 + quad * 4 + r];
        pA[ot][r] = pp.x; pB[ot][r] = pp.y;
      }
    const float alpha = P.a[0];
    #pragma unroll
    for (int i = 0; i < 4; ++i) {
      #pragma unroll
      for (int ot = 0; ot < 4; ++ot) {
        f32x4 acc = {0.f, 0.f, 0.f, 0.f};
        acc = __builtin_amdgcn_mfma_f32_16x16x32_bf16(A[ot][0], Bf[i][0], acc, 0, 0, 0);
        acc = __builtin_amdgcn_mfma_f32_16x16x32_bf16(A[ot][1], Bf[i][1], acc, 0, 0, 0);
        float y[4];
        #pragma unroll
        for (int r = 0; r < 4; ++r)
          y[r] = leaky(acc[r] * pA[ot][r] + pB[ot][r], alpha);
        // o = ot*16 + quad*4 + r;  even o -> Q ch o/2, odd -> K ch o/2
        const int ch0 = ot * 8 + quad * 2;
        *(unsigned*)&S0w[m16 * 40 + ch0] = (unsigned)f2bf(y[0]) | (((unsigned)f2bf(y[2])) << 16);
        *(unsigned*)&S1w[m16 * 40 + ch0] = (unsigned)f2bf(y[1]) | (((unsigned)f2bf(y[3])) << 16);
      }
      // emit own 16 rows (in-order DS per wave: writes above precede reads)
      const int trow = (wid * 4 + i) * 16 + r4;
      u32x4 qv = *(const u32x4*)&S0w[r4 * 40 + p4 * 8];
      u32x4 kv = *(const u32x4*)&S1w[r4 * 40 + p4 * 8];
      *(u32x4*)(Qd + tbase + (size_t)trow * 32 + p4 * 8) = qv;
      *(u32x4*)(Kd + tbase + (size_t)trow * 32 + p4 * 8) = kv;
    }
  };

  __syncthreads();                 // Xb(inp) + Pc ready

  bf16x8 Bf[4][2];
  #pragma unroll
  for (int i = 0; i < 4; ++i)
    #pragma unroll
    for (int ks = 0; ks < 2; ++ks) Bf[i][ks] = load_B(wid * 4 + i, ks);

  __syncthreads();                 // all waves done reading Xb(inp): Xb dead

  // ---- x prefetch, half 1 (channels 0..31): issue before fqk pass ----
  float4 xpre[8];
  #pragma unroll
  for (int r = 0; r < 8; ++r) {
    const int idx = r * 256 + tid;
    const int c = idx >> 6;
    const int t0 = (idx & 63) * 4;
    xpre[r] = *(const float4*)(x + gbase + (size_t)c * 65536 + t0);
  }

  qk_pass(fqk, 0, Bf, Qf, Kf);

  // ---- write x half 1 into Xb; issue half 2 (channels 32..63) ----
  #pragma unroll
  for (int r = 0; r < 8; ++r) {
    const int idx = r * 256 + tid;
    const int c = idx >> 6;
    const int t0 = (idx & 63) * 4;
    unsigned lo = (unsigned)f2bf(xpre[r].x) | (((unsigned)f2bf(xpre[r].y)) << 16);
    unsigned hi = (unsigned)f2bf(xpre[r].z) | (((unsigned)f2bf(xpre[r].w)) << 16);
    u32x2 pk = {lo, hi};
    *(u32x2*)&Xb[c * 260 + t0] = pk;
  }
  #pragma unroll
  for (int r = 0; r < 8; ++r) {
    const int idx = (r + 8) * 256 + tid;
    const int c = idx >> 6;
    const int t0 = (idx & 63) * 4;
    xpre[r] = *(const float4*)(x + gbase + (size_t)c * 65536 + t0);
  }

  qk_pass(tqk, 64, Bf, Qt, Kt);

  #pragma unroll
  for (int r = 0; r < 8; ++r) {
    const int idx = (r + 8) * 256 + tid;
    const int c = idx >> 6;
    const int t0 = (idx & 63) * 4;
    unsigned lo = (unsigned)f2bf(xpre[r].x) | (((unsigned)f2bf(xpre[r].y)) << 16);
    unsigned hi = (unsigned)f2bf(xpre[r].z) | (((unsigned)f2bf(xpre[r].w)) << 16);
    u32x2 pk = {lo, hi};
    *(u32x2*)&Xb[c * 260 + t0] = pk;
  }
  __syncthreads();                 // Xb(x) ready for all waves

  // ---- v pass: 32-row matrix, per-i wave-private emit ----
  {
    bf16x8 A[2][2], Bv[4][2];
    #pragma unroll
    for (int i = 0; i < 4; ++i)
      #pragma unroll
      for (int ks = 0; ks < 2; ++ks) Bv[i][ks] = load_B(wid * 4 + i, ks);
    #pragma unroll
    for (int ot = 0; ot < 2; ++ot)
      #pragma unroll
      for (int ks = 0; ks < 2; ++ks) A[ot][ks] = load_A(fv.W, ot * 16, ks);
    float pA[2][4], pB[2][4];
    #pragma unroll
    for (int ot = 0; ot < 2; ++ot)
      #pragma unroll
      for (int r = 0; r < 4; ++r) {
        const float2 pp = Pc[128 + ot * 16 + quad * 4 + r];
        pA[ot][r] = pp.x; pB[ot][r] = pp.y;
      }
    const float alpha = fv.a[0];
    #pragma unroll
    for (int i = 0; i < 4; ++i) {
      #pragma unroll
      for (int ot = 0; ot < 2; ++ot) {
        f32x4 acc = {0.f, 0.f, 0.f, 0.f};
        acc = __builtin_amdgcn_mfma_f32_16x16x32_bf16(A[ot][0], Bv[i][0], acc, 0, 0, 0);
        acc = __builtin_amdgcn_mfma_f32_16x16x32_bf16(A[ot][1], Bv[i][1], acc, 0, 0, 0);
        float y[4];
        #pragma unroll
        for (int r = 0; r < 4; ++r)
          y[r] = leaky(acc[r] * pA[ot][r] + pB[ot][r], alpha);
        const int ch = ot * 16 + quad * 4;
        *(unsigned*)&S0w[m16 * 40 + ch]     = (unsigned)f2bf(y[0]) | (((unsigned)f2bf(y[1])) << 16);
        *(unsigned*)&S0w[m16 * 40 + ch + 2] = (unsigned)f2bf(y[2]) | (((unsigned)f2bf(y[3])) << 16);
      }
      const int trow = (wid * 4 + i) * 16 + r4;
      u32x4 vv = *(const u32x4*)&S0w[r4 * 40 + p4 * 8];
      *(u32x4*)(Vf + tbase + (size_t)trow * 32 + p4 * 8) = vv;
    }
  }
}

// ---------------------------------------------------------------------------
// Attention kernel (v9, unchanged): SWAPPED QK^T.
//   acc[ct] = mfma(K-frag, Q-frag) => D col (lane&15) = q, row = k.
//   Lane owns 4 consecutive k of one P row per ct: packed 8-B P writes,
//   1-write causal pad, in-lane softmax partials + 2 shfl_xor.
//   PV path / staging / K-hoist / Q-prefetch / XCD swizzle: v7-identical.
// ---------------------------------------------------------------------------
template<bool CAUSAL>
__global__ __launch_bounds__(256, 2) void attn_k(
    const bf16* __restrict__ Qg, const bf16* __restrict__ Kg,
    const bf16* __restrict__ Vg, bf16* __restrict__ Og)
{
  __shared__ __attribute__((aligned(16))) unsigned short Kl[256 * 40];       // 20 KB, padded
  __shared__ __attribute__((aligned(16))) unsigned short Vt[32 * 264];       // V^T, stride 264
  __shared__ __attribute__((aligned(16))) unsigned short Plds[4][16 * 264];  // per-wave P
  __shared__ __attribute__((aligned(16))) unsigned short Wsc[4][16 * 40];    // per-wave Q/O scratch

  const int inst = swz1024(blockIdx.x);
  const int b = inst >> 8;
  const int s = inst & 255;
  constexpr int RS = CAUSAL ? 32 : 8192;             // row stride (elements)
  const int qbase = CAUSAL ? inst * 8192 : (b * 2097152 + s * 32);

  const int tid = threadIdx.x;
  const int lane = tid & 63;
  const int wid = tid >> 6;
  const int m16 = lane & 15;
  const int quad = lane >> 4;
  const int r4 = lane >> 2, p4 = lane & 3;

  // ---- Q prefetch: all 4 iterations' fragments, issued FIRST so their
  // latency overlaps K/V staging + barrier ----
  u32x4 qpre[4];
  #pragma unroll
  for (int it = 0; it < 4; ++it) {
    const int rt = wid + 4 * it;
    qpre[it] = *(const u32x4*)(Qg + qbase + (rt * 16 + r4) * RS + p4 * 8);
  }

  // ---- stage K tile (sector-dense cooperative load, padded rows) ----
  #pragma unroll
  for (int k2 = 0; k2 < 4; ++k2) {
    const int chunk = k2 * 256 + tid;            // 0..1023
    const int row = chunk >> 2, part = chunk & 3;
    u32x4 val = *(const u32x4*)(Kg + qbase + row * RS + part * 8);
    *(u32x4*)&Kl[row * 40 + part * 8] = val;
  }
  // ---- stage V transposed ----
  if (tid < 128) {
    const unsigned short* v0 = (const unsigned short*)(Vg + qbase) + (2 * tid) * RS;
    const unsigned short* v1 = v0 + RS;
    u16x8 a[4], c[4];
    #pragma unroll
    for (int q = 0; q < 4; ++q) {
      a[q] = *(const u16x8*)(v0 + 8 * q);
      c[q] = *(const u16x8*)(v1 + 8 * q);
    }
    unsigned int* vt32 = (unsigned int*)Vt;
    #pragma unroll
    for (int cc = 0; cc < 32; ++cc) {
      unsigned lo = a[cc >> 3][cc & 7];
      unsigned hi = c[cc >> 3][cc & 7];
      vt32[(cc * 264 + 2 * tid) >> 1] = lo | (hi << 16);
    }
  }
  __syncthreads();

  unsigned short* P  = &Plds[wid][0];
  unsigned short* Ws = &Wsc[wid][0];

  // ---- hoist all 16 K fragments into VGPRs (read once, used 4x) ----
  bf16x8 kfr[16];
  #pragma unroll
  for (int ct = 0; ct < 16; ++ct)
    kfr[ct] = *(const bf16x8*)&Kl[(ct * 16 + m16) * 40 + quad * 8];

  #pragma unroll 1
  for (int it = 0; it < 4; ++it) {
    const int rt = wid + 4 * it;
    // wave stages its prefetched Q tile into private scratch, then frag-reads
    {
      *(u32x4*)&Ws[r4 * 40 + p4 * 8] = qpre[it];
    }
    const bf16x8 qf = *(const bf16x8*)&Ws[m16 * 40 + quad * 8];
    const int nct = CAUSAL ? (rt + 1) : 16;

    // ---- SWAPPED QK^T: lane holds P[q = m16][k = ct*16 + quad*4 + r] ----
    f32x4 acc[16];
    #pragma unroll
    for (int ct = 0; ct < 16; ++ct) {
      if (ct < nct) {
        f32x4 z = {0.f, 0.f, 0.f, 0.f};
        acc[ct] = __builtin_amdgcn_mfma_f32_16x16x32_bf16(kfr[ct], qf, z, 0, 0, 0);
      }
    }
    // causal mask (k > q) + in-lane row-max partials.
    // Logits already in log2 domain (QS folded into Q at conv time).
    float mxr[4] = {-3e38f, -3e38f, -3e38f, -3e38f};
    #pragma unroll
    for (int ct = 0; ct < 16; ++ct) if (ct < nct) {
      #pragma unroll
      for (int r = 0; r < 4; ++r) {
        float v = acc[ct][r];
        if (CAUSAL && (ct == nct - 1) && (quad * 4 + r > m16)) v = -3e38f;
        acc[ct][r] = v;
        mxr[r] = fmaxf(mxr[r], v);
      }
    }
    float m = fmaxf(fmaxf(mxr[0], mxr[1]), fmaxf(mxr[2], mxr[3]));
    m = fmaxf(m, __shfl_xor(m, 16, 64));   // combine the 4 quads of column q
    m = fmaxf(m, __shfl_xor(m, 32, 64));
    float sr[4] = {0.f, 0.f, 0.f, 0.f};
    #pragma unroll
    for (int ct = 0; ct < 16; ++ct) if (ct < nct) {
      #pragma unroll
      for (int r = 0; r < 4; ++r) {
        float p = fast_exp2(acc[ct][r] - m);
        acc[ct][r] = p;
        sr[r] += p;
      }
    }
    float ssum = (sr[0] + sr[1]) + (sr[2] + sr[3]);
    ssum += __shfl_xor(ssum, 16, 64);
    ssum += __shfl_xor(ssum, 32, 64);
    const float inv = 1.0f / ssum;

    // write UNNORMALIZED P (bf16) to per-wave LDS: one packed 8-B write per
    // ct (row m16, cols ct*16 + quad*4 .. +3); inv applied in epilogue
    #pragma unroll
    for (int ct = 0; ct < 16; ++ct) if (ct < nct) {
      u32x2 pk = { (unsigned)f2bf(acc[ct][0]) | (((unsigned)f2bf(acc[ct][1])) << 16),
                   (unsigned)f2bf(acc[ct][2]) | (((unsigned)f2bf(acc[ct][3])) << 16) };
      *(u32x2*)&P[m16 * 264 + ct * 16 + quad * 4] = pk;
    }
    int ksteps = CAUSAL ? ((rt >> 1) + 1) : 8;
    if (CAUSAL && ((rt & 1) == 0)) {
      // zero tile ct=rt+1 so the K=32 MFMA step covering it reads zeros
      u32x2 z2 = {0u, 0u};
      *(u32x2*)&P[m16 * 264 + (rt + 1) * 16 + quad * 4] = z2;
    }
    // O = P * V  (A-frag: m=lane&15, k=quad*8+j; B-frag from Vt rows)
    f32x4 o0 = {0.f, 0.f, 0.f, 0.f}, o1 = {0.f, 0.f, 0.f, 0.f};
    #pragma unroll
    for (int ks = 0; ks < 8; ++ks) {
      if (ks < ksteps) {
        const bf16x8 pf  = *(const bf16x8*)&P[m16 * 264 + ks * 32 + quad * 8];
        const bf16x8 vf0 = *(const bf16x8*)&Vt[m16 * 264 + ks * 32 + quad * 8];
        const bf16x8 vf1 = *(const bf16x8*)&Vt[(16 + m16) * 264 + ks * 32 + quad * 8];
        o0 = __builtin_amdgcn_mfma_f32_16x16x32_bf16(pf, vf0, o0, 0, 0, 0);
        o1 = __builtin_amdgcn_mfma_f32_16x16x32_bf16(pf, vf1, o1, 0, 0, 0);
      }
    }
    // stage O tile (normalized here) in per-wave scratch, stream out dense.
    // o0[r] is q-row quad*4+r; its inv lives at lane (quad*4+r) of the 16-group.
    #pragma unroll
    for (int r = 0; r < 4; ++r) {
      const float invq = __shfl(inv, quad * 4 + r, 16);
      Ws[(quad * 4 + r) * 40 + m16]      = f2bf(o0[r] * invq);
      Ws[(quad * 4 + r) * 40 + 16 + m16] = f2bf(o1[r] * invq);
    }
    {
      u32x4 ov = *(const u32x4*)&Ws[r4 * 40 + p4 * 8];
      *(u32x4*)(Og + qbase + (rt * 16 + r4) * RS + p4 * 8) = ov;
    }
  }
}

// ---------------------------------------------------------------------------
// Kernel D (v7, unchanged): proj conv (32->64) + BN + LeakyReLU + residual,
// via 32x32x16 MFMA. C/D layout [m74/m101]: col=lane&31,
// row=(reg&3)+8*(reg>>2)+4*(lane>>5).
// ---------------------------------------------------------------------------
__global__ __launch_bounds__(256) void proj_k(
    const bf16* __restrict__ tout, const float* __restrict__ x,
    ConvP pj, float* __restrict__ out)
{
  __shared__ float2 Pc[64];
  const int tid = threadIdx.x;
  const int id = swz1024(blockIdx.x);
  const int b = id >> 8;
  const int f = id & 255;
  if (tid < 64) {
    const float A = pj.g[tid] * rsqrtf(pj.v[tid] + 1e-5f);
    const float B2 = (pj.bi[tid] - pj.m[tid]) * A + pj.be[tid];
    Pc[tid] = make_float2(A, B2);
  }
  const int lane = tid & 63;
  const int wid = tid >> 6;
  const int n32 = lane & 31;
  const int h = lane >> 5;          // k-half selector

  // A-frags: W[o = ot*32+n32][k = ks*16 + h*8 + j]  (fp32 -> bf16)
  bf16x8 Afr[2][2];
  #pragma unroll
  for (int ot = 0; ot < 2; ++ot)
    #pragma unroll
    for (int ks = 0; ks < 2; ++ks) {
      const float* p = pj.W + (ot * 32 + n32) * 32 + ks * 16 + h * 8;
      const float4 lo = *(const float4*)p;
      const float4 hi = *(const float4*)(p + 4);
      bf16x8 r;
      r[0] = (short)f2bf(lo.x); r[1] = (short)f2bf(lo.y);
      r[2] = (short)f2bf(lo.z); r[3] = (short)f2bf(lo.w);
      r[4] = (short)f2bf(hi.x); r[5] = (short)f2bf(hi.y);
      r[6] = (short)f2bf(hi.z); r[7] = (short)f2bf(hi.w);
      Afr[ot][ks] = r;
    }
  __syncthreads();

  const float alpha = pj.a[0];
  const size_t gbase = (size_t)b * 64 * 65536 + f * 256;  // x/out: + o*65536 + t
  const size_t tbase = (size_t)(b * 256 + f) * 8192;      // tout tile base

  #pragma unroll
  for (int tt = 0; tt < 2; ++tt) {
    const int t = wid * 64 + tt * 32 + n32;
    // B-frags: tout[t][k = ks*16 + h*8 + j] — direct global, rows contiguous
    const bf16x8 B0 = *(const bf16x8*)(tout + tbase + (size_t)t * 32 + 0 * 16 + h * 8);
    const bf16x8 B1 = *(const bf16x8*)(tout + tbase + (size_t)t * 32 + 1 * 16 + h * 8);
    #pragma unroll
    for (int ot = 0; ot < 2; ++ot) {
      f32x16 acc = {};
      acc = __builtin_amdgcn_mfma_f32_32x32x16_bf16(Afr[ot][0], B0, acc, 0, 0, 0);
      acc = __builtin_amdgcn_mfma_f32_32x32x16_bf16(Afr[ot][1], B1, acc, 0, 0, 0);
      #pragma unroll
      for (int reg = 0; reg < 16; ++reg) {
        const int o = ot * 32 + (reg & 3) + 8 * (reg >> 2) + 4 * h;
        const float2 pp = Pc[o];
        float y = acc[reg] * pp.x + pp.y;
        y = y > 0.f ? y : alpha * y;
        const size_t off = gbase + (size_t)o * 65536 + t;
        out[off] = y + x[off];
      }
    }
  }
}

extern "C" void kernel_launch(void* const* d_in, const int* in_sizes, int n_in,
                              void* d_out, int out_size, void* d_ws, size_t ws_size,
                              hipStream_t stream) {
  const float* inp = (const float*)d_in[0];
  const float* x   = (const float*)d_in[1];
  auto cp = [&](int i) {
    return ConvP{ (const float*)d_in[i],     (const float*)d_in[i + 1],
                  (const float*)d_in[i + 2], (const float*)d_in[i + 3],
                  (const float*)d_in[i + 4], (const float*)d_in[i + 5],
                  (const float*)d_in[i + 6] };
  };
  ConvP fqk = cp(2), fv = cp(9), tqk = cp(16), pj = cp(23);

  char* ws = (char*)d_ws;
  const size_t SZ = (size_t)4 * 256 * 256 * 32 * 2;  // 16 MiB per bf16 buffer
  bf16* Qf = (bf16*)(ws + 0 * SZ);   // (B,F,T,CH)
  bf16* Kf = (bf16*)(ws + 1 * SZ);
  bf16* Vf = (bf16*)(ws + 2 * SZ);
  bf16* Qt = (bf16*)(ws + 3 * SZ);
  bf16* Kt = (bf16*)(ws + 4 * SZ);
  bf16* Ft = (bf16*)(ws + 5 * SZ);   // fout (B,F,T,CH)
  bf16* To = (bf16*)(ws + 0 * SZ);   // tout reuses Qf (dead after f-attn)

  conv_qkv<<<1024, 256, 0, stream>>>(inp, x, fqk, fv, tqk, Qf, Kf, Vf, Qt, Kt);
  attn_k<false><<<1024, 256, 0, stream>>>(Qf, Kf, Vf, Ft);   // freq attention
  attn_k<true><<<1024, 256, 0, stream>>>(Qt, Kt, Ft, To);    // causal time attention
  proj_k<<<1024, 256, 0, stream>>>(To, x, pj, (float*)d_out);
}

// Round 6
// 309.676 us; speedup vs baseline: 1.0662x; 1.0662x over previous
//
#include <hip/hip_runtime.h>
#include <hip/hip_bf16.h>

// Problem constants: B=4, C=64, F=256, T=256, CH=32
typedef __hip_bfloat16 bf16;
typedef __attribute__((ext_vector_type(8))) short bf16x8;
typedef __attribute__((ext_vector_type(4))) float f32x4;
typedef __attribute__((ext_vector_type(16))) float f32x16;
typedef __attribute__((ext_vector_type(8))) unsigned short u16x8;
typedef __attribute__((ext_vector_type(4))) unsigned int u32x4;
typedef __attribute__((ext_vector_type(2))) unsigned int u32x2;

struct ConvP {
  const float* W; const float* bi; const float* g; const float* be;
  const float* m; const float* v; const float* a;
};

// 1/sqrt(32) * log2(e): folded into Q-channel BN params (leaky ReLU is
// positively homogeneous so scale commutes); attention then uses raw exp2.
#define QS (0.17677669529663687f * 1.4426950408889634f)

// m204-style bijective XCD swizzle for a 1024-block grid on 8 XCDs.
// Used in attn/proj only (conv measured -4% with it in R2).
__device__ __forceinline__ int swz1024(int i) {
  return ((i & 7) << 7) | (i >> 3);
}

__device__ __forceinline__ unsigned short f2bf(float f) {
  __hip_bfloat16 h = __float2bfloat16(f);
  return __builtin_bit_cast(unsigned short, h);
}
__device__ __forceinline__ float fast_exp2(float x) {
#if __has_builtin(__builtin_amdgcn_exp2f)
  return __builtin_amdgcn_exp2f(x);
#else
  return exp2f(x);
#endif
}

// ---------------------------------------------------------------------------
// Kernel A (v5, R0-exact — FROZEN): fused 1x1 conv + BN + LeakyReLU via
// 16x16x32 MFMA. Every restructure attempted (v6 half-tile, v8 direct
// stores, v10 per-wave emit) inflated FETCH/WRITE; this structure is the
// only one measuring exactly-ideal traffic (WRITE 81920 KB). Do not touch.
// ---------------------------------------------------------------------------
__global__ __launch_bounds__(256, 2) void conv_qkv(
    const float* __restrict__ inp, const float* __restrict__ x,
    ConvP fqk, ConvP fv, ConvP tqk,
    bf16* __restrict__ Qf, bf16* __restrict__ Kf, bf16* __restrict__ Vf,
    bf16* __restrict__ Qt, bf16* __restrict__ Kt)
{
  __shared__ __attribute__((aligned(16))) unsigned short Xb[64 * 260]; // 33.3 KB
  __shared__ __attribute__((aligned(16))) unsigned short S0[256 * 40]; // 20 KB
  __shared__ __attribute__((aligned(16))) unsigned short S1[256 * 40]; // 20 KB
  __shared__ __attribute__((aligned(8)))  float2 Pc[160];              // BN (A,B) per o

  const int tid = threadIdx.x;
  const int b = blockIdx.x >> 8;
  const int f = blockIdx.x & 255;
  const size_t gbase = (size_t)b * 64 * 65536 + f * 256;   // (b, c=0, f, t=0)
  const size_t tbase = (size_t)(b * 256 + f) * 8192;       // output tile base

  const int lane = tid & 63;
  const int wid = tid >> 6;
  const int m16 = lane & 15;
  const int quad = lane >> 4;

  // ---- BN param table: Pc[o] = (A, B2) with y = conv*A + B2 ----
  if (tid < 160) {
    const ConvP& P = (tid < 64) ? fqk : (tid < 128) ? tqk : fv;
    const int o = (tid < 64) ? tid : (tid < 128) ? tid - 64 : tid - 128;
    float A = P.g[o] * rsqrtf(P.v[o] + 1e-5f);
    float B2 = (P.bi[o] - P.m[o]) * A + P.be[o];
    if (tid < 128 && ((o & 1) == 0)) { A *= QS; B2 *= QS; }  // Q channels
    Pc[tid] = make_float2(A, B2);
  }

  // ---- stage an X tile (fp32 global -> bf16 LDS [c][t], stride 260) ----
  auto load_X = [&](const float* __restrict__ src) {
    #pragma unroll
    for (int r = 0; r < 16; ++r) {
      const int idx = r * 256 + tid;
      const int c = idx >> 6;
      const int t0 = (idx & 63) * 4;
      const float4 v = *(const float4*)(src + gbase + (size_t)c * 65536 + t0);
      unsigned lo = (unsigned)f2bf(v.x) | (((unsigned)f2bf(v.y)) << 16);
      unsigned hi = (unsigned)f2bf(v.z) | (((unsigned)f2bf(v.w)) << 16);
      u32x2 pk = {lo, hi};
      *(u32x2*)&Xb[c * 260 + t0] = pk;
    }
  };

  // ---- A-frag: W[o = rowbase+m16][k = ks*32+quad*8+j] (fp32 -> bf16) ----
  auto load_A = [&](const float* __restrict__ W, int rowbase, int ks) {
    const float* p = W + (rowbase + m16) * 64 + ks * 32 + quad * 8;
    const float4 lo = *(const float4*)p;
    const float4 hi = *(const float4*)(p + 4);
    bf16x8 r;
    r[0] = (short)f2bf(lo.x); r[1] = (short)f2bf(lo.y);
    r[2] = (short)f2bf(lo.z); r[3] = (short)f2bf(lo.w);
    r[4] = (short)f2bf(hi.x); r[5] = (short)f2bf(hi.y);
    r[6] = (short)f2bf(hi.z); r[7] = (short)f2bf(hi.w);
    return r;
  };

  // ---- B-frag: X[t = tt*16+m16][k = ks*32+quad*8+j] from LDS ----
  auto load_B = [&](int tt, int ks) {
    const int t = tt * 16 + m16;
    const int i0 = ks * 32 + quad * 8;
    bf16x8 r;
    #pragma unroll
    for (int j = 0; j < 8; ++j) r[j] = (short)Xb[(i0 + j) * 260 + t];
    return r;
  };

  // ---- stream a staged [256 t][32 ch] (stride 40) buffer out lane-dense ----
  auto emit = [&](const unsigned short* S, bf16* __restrict__ dst) {
    #pragma unroll
    for (int r = 0; r < 4; ++r) {
      const int chunk = r * 256 + tid;           // 16 B units
      const int t = chunk >> 2, part = chunk & 3;
      u32x4 v = *(const u32x4*)&S[t * 40 + part * 8];
      *(u32x4*)(dst + tbase + (size_t)chunk * 8) = v;
    }
  };

  auto leaky = [](float y, float alpha) { return y > 0.f ? y : alpha * y; };

  // ---- qk pass: 64-row matrix, de-interleave even->S0 (Q), odd->S1 (K) ----
  auto qk_pass = [&](const ConvP& P, int pcb, const bf16x8 (&Bf)[4][2]) {
    bf16x8 A[4][2];
    #pragma unroll
    for (int ot = 0; ot < 4; ++ot)
      #pragma unroll
      for (int ks = 0; ks < 2; ++ks) A[ot][ks] = load_A(P.W, ot * 16, ks);
    float pA[4][4], pB[4][4];
    #pragma unroll
    for (int ot = 0; ot < 4; ++ot)
      #pragma unroll
      for (int r = 0; r < 4; ++r) {
        const float2 pp = Pc[pcb + ot * 16 + quad * 4 + r];
        pA[ot][r] = pp.x; pB[ot][r] = pp.y;
      }
    const float alpha = P.a[0];
    #pragma unroll
    for (int i = 0; i < 4; ++i) {
      const int t = (wid * 4 + i) * 16 + m16;
      #pragma unroll
      for (int ot = 0; ot < 4; ++ot) {
        f32x4 acc = {0.f, 0.f, 0.f, 0.f};
        acc = __builtin_amdgcn_mfma_f32_16x16x32_bf16(A[ot][0], Bf[i][0], acc, 0, 0, 0);
        acc = __builtin_amdgcn_mfma_f32_16x16x32_bf16(A[ot][1], Bf[i][1], acc, 0, 0, 0);
        float y[4];
        #pragma unroll
        for (int r = 0; r < 4; ++r)
          y[r] = leaky(acc[r] * pA[ot][r] + pB[ot][r], alpha);
        // o = ot*16 + quad*4 + r;  even o -> Q ch o/2, odd -> K ch o/2
        const int ch0 = ot * 8 + quad * 2;
        *(unsigned*)&S0[t * 40 + ch0] = (unsigned)f2bf(y[0]) | (((unsigned)f2bf(y[2])) << 16);
        *(unsigned*)&S1[t * 40 + ch0] = (unsigned)f2bf(y[1]) | (((unsigned)f2bf(y[3])) << 16);
      }
    }
  };

  load_X(inp);
  __syncthreads();                 // Xb + Pc ready

  bf16x8 Bf[4][2];
  #pragma unroll
  for (int i = 0; i < 4; ++i)
    #pragma unroll
    for (int ks = 0; ks < 2; ++ks) Bf[i][ks] = load_B(wid * 4 + i, ks);

  qk_pass(fqk, 0, Bf);
  __syncthreads();
  emit(S0, Qf); emit(S1, Kf);
  __syncthreads();
  qk_pass(tqk, 64, Bf);
  __syncthreads();
  emit(S0, Qt); emit(S1, Kt);
  __syncthreads();
  load_X(x);                       // overwrite Xb with x tile
  __syncthreads();

  // ---- v pass: 32-row matrix -> S0 ----
  {
    bf16x8 A[2][2], Bv[4][2];
    #pragma unroll
    for (int i = 0; i < 4; ++i)
      #pragma unroll
      for (int ks = 0; ks < 2; ++ks) Bv[i][ks] = load_B(wid * 4 + i, ks);
    #pragma unroll
    for (int ot = 0; ot < 2; ++ot)
      #pragma unroll
      for (int ks = 0; ks < 2; ++ks) A[ot][ks] = load_A(fv.W, ot * 16, ks);
    float pA[2][4], pB[2][4];
    #pragma unroll
    for (int ot = 0; ot < 2; ++ot)
      #pragma unroll
      for (int r = 0; r < 4; ++r) {
        const float2 pp = Pc[128 + ot * 16 + quad * 4 + r];
        pA[ot][r] = pp.x; pB[ot][r] = pp.y;
      }
    const float alpha = fv.a[0];
    #pragma unroll
    for (int i = 0; i < 4; ++i) {
      const int t = (wid * 4 + i) * 16 + m16;
      #pragma unroll
      for (int ot = 0; ot < 2; ++ot) {
        f32x4 acc = {0.f, 0.f, 0.f, 0.f};
        acc = __builtin_amdgcn_mfma_f32_16x16x32_bf16(A[ot][0], Bv[i][0], acc, 0, 0, 0);
        acc = __builtin_amdgcn_mfma_f32_16x16x32_bf16(A[ot][1], Bv[i][1], acc, 0, 0, 0);
        float y[4];
        #pragma unroll
        for (int r = 0; r < 4; ++r)
          y[r] = leaky(acc[r] * pA[ot][r] + pB[ot][r], alpha);
        const int ch = ot * 16 + quad * 4;
        *(unsigned*)&S0[t * 40 + ch]     = (unsigned)f2bf(y[0]) | (((unsigned)f2bf(y[1])) << 16);
        *(unsigned*)&S0[t * 40 + ch + 2] = (unsigned)f2bf(y[2]) | (((unsigned)f2bf(y[3])) << 16);
      }
    }
  }
  __syncthreads();
  emit(S0, Vf);
}

// ---------------------------------------------------------------------------
// f-attention kernel (v9, unchanged): SWAPPED QK^T, instance (b,t), strided
// rows (RS=8192). Only instantiated with CAUSAL=false now.
// ---------------------------------------------------------------------------
template<bool CAUSAL>
__global__ __launch_bounds__(256, 2) void attn_k(
    const bf16* __restrict__ Qg, const bf16* __restrict__ Kg,
    const bf16* __restrict__ Vg, bf16* __restrict__ Og)
{
  __shared__ __attribute__((aligned(16))) unsigned short Kl[256 * 40];       // 20 KB, padded
  __shared__ __attribute__((aligned(16))) unsigned short Vt[32 * 264];       // V^T, stride 264
  __shared__ __attribute__((aligned(16))) unsigned short Plds[4][16 * 264];  // per-wave P
  __shared__ __attribute__((aligned(16))) unsigned short Wsc[4][16 * 40];    // per-wave Q/O scratch

  const int inst = swz1024(blockIdx.x);
  const int b = inst >> 8;
  const int s = inst & 255;
  constexpr int RS = CAUSAL ? 32 : 8192;             // row stride (elements)
  const int qbase = CAUSAL ? inst * 8192 : (b * 2097152 + s * 32);

  const int tid = threadIdx.x;
  const int lane = tid & 63;
  const int wid = tid >> 6;
  const int m16 = lane & 15;
  const int quad = lane >> 4;
  const int r4 = lane >> 2, p4 = lane & 3;

  u32x4 qpre[4];
  #pragma unroll
  for (int it = 0; it < 4; ++it) {
    const int rt = wid + 4 * it;
    qpre[it] = *(const u32x4*)(Qg + qbase + (rt * 16 + r4) * RS + p4 * 8);
  }

  #pragma unroll
  for (int k2 = 0; k2 < 4; ++k2) {
    const int chunk = k2 * 256 + tid;            // 0..1023
    const int row = chunk >> 2, part = chunk & 3;
    u32x4 val = *(const u32x4*)(Kg + qbase + row * RS + part * 8);
    *(u32x4*)&Kl[row * 40 + part * 8] = val;
  }
  if (tid < 128) {
    const unsigned short* v0 = (const unsigned short*)(Vg + qbase) + (2 * tid) * RS;
    const unsigned short* v1 = v0 + RS;
    u16x8 a[4], c[4];
    #pragma unroll
    for (int q = 0; q < 4; ++q) {
      a[q] = *(const u16x8*)(v0 + 8 * q);
      c[q] = *(const u16x8*)(v1 + 8 * q);
    }
    unsigned int* vt32 = (unsigned int*)Vt;
    #pragma unroll
    for (int cc = 0; cc < 32; ++cc) {
      unsigned lo = a[cc >> 3][cc & 7];
      unsigned hi = c[cc >> 3][cc & 7];
      vt32[(cc * 264 + 2 * tid) >> 1] = lo | (hi << 16);
    }
  }
  __syncthreads();

  unsigned short* P  = &Plds[wid][0];
  unsigned short* Ws = &Wsc[wid][0];

  bf16x8 kfr[16];
  #pragma unroll
  for (int ct = 0; ct < 16; ++ct)
    kfr[ct] = *(const bf16x8*)&Kl[(ct * 16 + m16) * 40 + quad * 8];

  #pragma unroll 1
  for (int it = 0; it < 4; ++it) {
    const int rt = wid + 4 * it;
    {
      *(u32x4*)&Ws[r4 * 40 + p4 * 8] = qpre[it];
    }
    const bf16x8 qf = *(const bf16x8*)&Ws[m16 * 40 + quad * 8];
    const int nct = CAUSAL ? (rt + 1) : 16;

    f32x4 acc[16];
    #pragma unroll
    for (int ct = 0; ct < 16; ++ct) {
      if (ct < nct) {
        f32x4 z = {0.f, 0.f, 0.f, 0.f};
        acc[ct] = __builtin_amdgcn_mfma_f32_16x16x32_bf16(kfr[ct], qf, z, 0, 0, 0);
      }
    }
    float mxr[4] = {-3e38f, -3e38f, -3e38f, -3e38f};
    #pragma unroll
    for (int ct = 0; ct < 16; ++ct) if (ct < nct) {
      #pragma unroll
      for (int r = 0; r < 4; ++r) {
        float v = acc[ct][r];
        if (CAUSAL && (ct == nct - 1) && (quad * 4 + r > m16)) v = -3e38f;
        acc[ct][r] = v;
        mxr[r] = fmaxf(mxr[r], v);
      }
    }
    float m = fmaxf(fmaxf(mxr[0], mxr[1]), fmaxf(mxr[2], mxr[3]));
    m = fmaxf(m, __shfl_xor(m, 16, 64));
    m = fmaxf(m, __shfl_xor(m, 32, 64));
    float sr[4] = {0.f, 0.f, 0.f, 0.f};
    #pragma unroll
    for (int ct = 0; ct < 16; ++ct) if (ct < nct) {
      #pragma unroll
      for (int r = 0; r < 4; ++r) {
        float p = fast_exp2(acc[ct][r] - m);
        acc[ct][r] = p;
        sr[r] += p;
      }
    }
    float ssum = (sr[0] + sr[1]) + (sr[2] + sr[3]);
    ssum += __shfl_xor(ssum, 16, 64);
    ssum += __shfl_xor(ssum, 32, 64);
    const float inv = 1.0f / ssum;

    #pragma unroll
    for (int ct = 0; ct < 16; ++ct) if (ct < nct) {
      u32x2 pk = { (unsigned)f2bf(acc[ct][0]) | (((unsigned)f2bf(acc[ct][1])) << 16),
                   (unsigned)f2bf(acc[ct][2]) | (((unsigned)f2bf(acc[ct][3])) << 16) };
      *(u32x2*)&P[m16 * 264 + ct * 16 + quad * 4] = pk;
    }
    int ksteps = CAUSAL ? ((rt >> 1) + 1) : 8;
    if (CAUSAL && ((rt & 1) == 0)) {
      u32x2 z2 = {0u, 0u};
      *(u32x2*)&P[m16 * 264 + (rt + 1) * 16 + quad * 4] = z2;
    }
    f32x4 o0 = {0.f, 0.f, 0.f, 0.f}, o1 = {0.f, 0.f, 0.f, 0.f};
    #pragma unroll
    for (int ks = 0; ks < 8; ++ks) {
      if (ks < ksteps) {
        const bf16x8 pf  = *(const bf16x8*)&P[m16 * 264 + ks * 32 + quad * 8];
        const bf16x8 vf0 = *(const bf16x8*)&Vt[m16 * 264 + ks * 32 + quad * 8];
        const bf16x8 vf1 = *(const bf16x8*)&Vt[(16 + m16) * 264 + ks * 32 + quad * 8];
        o0 = __builtin_amdgcn_mfma_f32_16x16x32_bf16(pf, vf0, o0, 0, 0, 0);
        o1 = __builtin_amdgcn_mfma_f32_16x16x32_bf16(pf, vf1, o1, 0, 0, 0);
      }
    }
    #pragma unroll
    for (int r = 0; r < 4; ++r) {
      const float invq = __shfl(inv, quad * 4 + r, 16);
      Ws[(quad * 4 + r) * 40 + m16]      = f2bf(o0[r] * invq);
      Ws[(quad * 4 + r) * 40 + 16 + m16] = f2bf(o1[r] * invq);
    }
    {
      u32x4 ov = *(const u32x4*)&Ws[r4 * 40 + p4 * 8];
      *(u32x4*)(Og + qbase + (rt * 16 + r4) * RS + p4 * 8) = ov;
    }
  }
}

// ---------------------------------------------------------------------------
// FUSED t-attention + proj (v11). t-attn instance (b,f) produces exactly the
// [256 t][32 ch] tile proj block (b,f) consumes -> keep O in LDS Ob, run the
// proj phase in the same block. Saves the 16 MiB To write + 16 MiB read + a
// launch. To fit 2 blocks/CU (79 KB), Plds uses v6's PROVEN half-K
// time-share: write P for ct 0-7 -> PV ks 0-3 -> overwrite with ct 8-15 ->
// ks 4-7 (per-wave in-order DS; same accumulation order -> bit-identical).
// Attn math identical to v9 (swapped QK^T, in-lane softmax).
// ---------------------------------------------------------------------------
__global__ __launch_bounds__(256, 2) void attn_proj(
    const bf16* __restrict__ Qg, const bf16* __restrict__ Kg,
    const bf16* __restrict__ Vg, ConvP pj,
    const float* __restrict__ x, float* __restrict__ out)
{
  __shared__ __attribute__((aligned(16))) unsigned short Kl[256 * 40];       // 20 KB
  __shared__ __attribute__((aligned(16))) unsigned short Vt[32 * 264];       // 16.5 KB
  __shared__ __attribute__((aligned(16))) unsigned short Plds[4][16 * 136];  // 17 KB (half-K)
  __shared__ __attribute__((aligned(16))) unsigned short Wsc[4][16 * 40];    // 5 KB (Q scratch)
  __shared__ __attribute__((aligned(16))) unsigned short Ob[256 * 40];       // 20 KB (O tile)
  __shared__ __attribute__((aligned(8)))  float2 Pc[64];

  const int inst = swz1024(blockIdx.x);
  const int b = inst >> 8;
  const int f = inst & 255;
  const int qbase = inst * 8192;     // causal layout: row r at qbase + r*32

  const int tid = threadIdx.x;
  const int lane = tid & 63;
  const int wid = tid >> 6;
  const int m16 = lane & 15;
  const int quad = lane >> 4;
  const int r4 = lane >> 2, p4 = lane & 3;

  // proj BN table (read after the attn->proj barrier)
  if (tid < 64) {
    const float A = pj.g[tid] * rsqrtf(pj.v[tid] + 1e-5f);
    const float B2 = (pj.bi[tid] - pj.m[tid]) * A + pj.be[tid];
    Pc[tid] = make_float2(A, B2);
  }

  // ---- Q prefetch (overlaps K/V staging + barrier) ----
  u32x4 qpre[4];
  #pragma unroll
  for (int it = 0; it < 4; ++it) {
    const int rt = wid + 4 * it;
    qpre[it] = *(const u32x4*)(Qg + qbase + (rt * 16 + r4) * 32 + p4 * 8);
  }

  // ---- stage K tile ----
  #pragma unroll
  for (int k2 = 0; k2 < 4; ++k2) {
    const int chunk = k2 * 256 + tid;
    const int row = chunk >> 2, part = chunk & 3;
    u32x4 val = *(const u32x4*)(Kg + qbase + row * 32 + part * 8);
    *(u32x4*)&Kl[row * 40 + part * 8] = val;
  }
  // ---- stage V transposed ----
  if (tid < 128) {
    const unsigned short* v0 = (const unsigned short*)(Vg + qbase) + (2 * tid) * 32;
    const unsigned short* v1 = v0 + 32;
    u16x8 a[4], c[4];
    #pragma unroll
    for (int q = 0; q < 4; ++q) {
      a[q] = *(const u16x8*)(v0 + 8 * q);
      c[q] = *(const u16x8*)(v1 + 8 * q);
    }
    unsigned int* vt32 = (unsigned int*)Vt;
    #pragma unroll
    for (int cc = 0; cc < 32; ++cc) {
      unsigned lo = a[cc >> 3][cc & 7];
      unsigned hi = c[cc >> 3][cc & 7];
      vt32[(cc * 264 + 2 * tid) >> 1] = lo | (hi << 16);
    }
  }
  __syncthreads();

  unsigned short* P  = &Plds[wid][0];
  unsigned short* Ws = &Wsc[wid][0];

  bf16x8 kfr[16];
  #pragma unroll
  for (int ct = 0; ct < 16; ++ct)
    kfr[ct] = *(const bf16x8*)&Kl[(ct * 16 + m16) * 40 + quad * 8];

  #pragma unroll 1
  for (int it = 0; it < 4; ++it) {
    const int rt = wid + 4 * it;
    {
      *(u32x4*)&Ws[r4 * 40 + p4 * 8] = qpre[it];
    }
    const bf16x8 qf = *(const bf16x8*)&Ws[m16 * 40 + quad * 8];
    const int nct = rt + 1;

    // SWAPPED QK^T: lane holds P[q=m16][k = ct*16 + quad*4 + r]
    f32x4 acc[16];
    #pragma unroll
    for (int ct = 0; ct < 16; ++ct) {
      if (ct < nct) {
        f32x4 z = {0.f, 0.f, 0.f, 0.f};
        acc[ct] = __builtin_amdgcn_mfma_f32_16x16x32_bf16(kfr[ct], qf, z, 0, 0, 0);
      }
    }
    float mxr[4] = {-3e38f, -3e38f, -3e38f, -3e38f};
    #pragma unroll
    for (int ct = 0; ct < 16; ++ct) if (ct < nct) {
      #pragma unroll
      for (int r = 0; r < 4; ++r) {
        float v = acc[ct][r];
        if ((ct == nct - 1) && (quad * 4 + r > m16)) v = -3e38f;
        acc[ct][r] = v;
        mxr[r] = fmaxf(mxr[r], v);
      }
    }
    float m = fmaxf(fmaxf(mxr[0], mxr[1]), fmaxf(mxr[2], mxr[3]));
    m = fmaxf(m, __shfl_xor(m, 16, 64));
    m = fmaxf(m, __shfl_xor(m, 32, 64));
    float sr[4] = {0.f, 0.f, 0.f, 0.f};
    #pragma unroll
    for (int ct = 0; ct < 16; ++ct) if (ct < nct) {
      #pragma unroll
      for (int r = 0; r < 4; ++r) {
        float p = fast_exp2(acc[ct][r] - m);
        acc[ct][r] = p;
        sr[r] += p;
      }
    }
    float ssum = (sr[0] + sr[1]) + (sr[2] + sr[3]);
    ssum += __shfl_xor(ssum, 16, 64);
    ssum += __shfl_xor(ssum, 32, 64);
    const float inv = 1.0f / ssum;

    const int ksteps = (rt >> 1) + 1;
    f32x4 o0 = {0.f, 0.f, 0.f, 0.f}, o1 = {0.f, 0.f, 0.f, 0.f};
    // ---- half-K time-share of Plds: half hh covers ct 8hh..+7 / ks 4hh..+3
    #pragma unroll
    for (int hh = 0; hh < 2; ++hh) {
      if (8 * hh < nct) {
        #pragma unroll
        for (int c2 = 0; c2 < 8; ++c2) {
          const int ct = 8 * hh + c2;
          if (ct < nct) {
            u32x2 pk = { (unsigned)f2bf(acc[ct][0]) | (((unsigned)f2bf(acc[ct][1])) << 16),
                         (unsigned)f2bf(acc[ct][2]) | (((unsigned)f2bf(acc[ct][3])) << 16) };
            *(u32x2*)&P[m16 * 136 + c2 * 16 + quad * 4] = pk;
          }
        }
        if (((rt & 1) == 0) && (((rt + 1) >> 3) == hh)) {
          // zero tile ct=rt+1 so the K=32 MFMA step covering it reads zeros
          u32x2 z2 = {0u, 0u};
          *(u32x2*)&P[m16 * 136 + ((rt + 1) & 7) * 16 + quad * 4] = z2;
        }
        #pragma unroll
        for (int k4 = 0; k4 < 4; ++k4) {
          const int ks = 4 * hh + k4;
          if (ks < ksteps) {
            const bf16x8 pf  = *(const bf16x8*)&P[m16 * 136 + k4 * 32 + quad * 8];
            const bf16x8 vf0 = *(const bf16x8*)&Vt[m16 * 264 + ks * 32 + quad * 8];
            const bf16x8 vf1 = *(const bf16x8*)&Vt[(16 + m16) * 264 + ks * 32 + quad * 8];
            o0 = __builtin_amdgcn_mfma_f32_16x16x32_bf16(pf, vf0, o0, 0, 0, 0);
            o1 = __builtin_amdgcn_mfma_f32_16x16x32_bf16(pf, vf1, o1, 0, 0, 0);
          }
        }
      }
    }
    // ---- O (normalized) -> block-shared Ob[256][40]; no global store ----
    #pragma unroll
    for (int r = 0; r < 4; ++r) {
      const float invq = __shfl(inv, quad * 4 + r, 16);
      const int row = rt * 16 + quad * 4 + r;
      Ob[row * 40 + m16]      = f2bf(o0[r] * invq);
      Ob[row * 40 + 16 + m16] = f2bf(o1[r] * invq);
    }
  }
  __syncthreads();                 // Ob complete; Pc ready

  // ---- proj phase: conv(32->64) + BN + LeakyReLU + residual, B from Ob ----
  {
    const int n32 = lane & 31;
    const int kh = lane >> 5;       // k-half selector
    bf16x8 Afr[2][2];
    #pragma unroll
    for (int ot = 0; ot < 2; ++ot)
      #pragma unroll
      for (int ks = 0; ks < 2; ++ks) {
        const float* p = pj.W + (ot * 32 + n32) * 32 + ks * 16 + kh * 8;
        const float4 lo = *(const float4*)p;
        const float4 hi = *(const float4*)(p + 4);
        bf16x8 r;
        r[0] = (short)f2bf(lo.x); r[1] = (short)f2bf(lo.y);
        r[2] = (short)f2bf(lo.z); r[3] = (short)f2bf(lo.w);
        r[4] = (short)f2bf(hi.x); r[5] = (short)f2bf(hi.y);
        r[6] = (short)f2bf(hi.z); r[7] = (short)f2bf(hi.w);
        Afr[ot][ks] = r;
      }
    const float alpha = pj.a[0];
    const size_t gbase = (size_t)b * 64 * 65536 + f * 256;  // x/out base

    #pragma unroll
    for (int tt = 0; tt < 2; ++tt) {
      const int t = wid * 64 + tt * 32 + n32;
      const bf16x8 B0 = *(const bf16x8*)&Ob[t * 40 + 0 * 16 + kh * 8];
      const bf16x8 B1 = *(const bf16x8*)&Ob[t * 40 + 1 * 16 + kh * 8];
      #pragma unroll
      for (int ot = 0; ot < 2; ++ot) {
        f32x16 acc = {};
        acc = __builtin_amdgcn_mfma_f32_32x32x16_bf16(Afr[ot][0], B0, acc, 0, 0, 0);
        acc = __builtin_amdgcn_mfma_f32_32x32x16_bf16(Afr[ot][1], B1, acc, 0, 0, 0);
        #pragma unroll
        for (int reg = 0; reg < 16; ++reg) {
          const int o = ot * 32 + (reg & 3) + 8 * (reg >> 2) + 4 * kh;
          const float2 pp = Pc[o];
          float y = acc[reg] * pp.x + pp.y;
          y = y > 0.f ? y : alpha * y;
          const size_t off = gbase + (size_t)o * 65536 + t;
          out[off] = y + x[off];
        }
      }
    }
  }
}

extern "C" void kernel_launch(void* const* d_in, const int* in_sizes, int n_in,
                              void* d_out, int out_size, void* d_ws, size_t ws_size,
                              hipStream_t stream) {
  const float* inp = (const float*)d_in[0];
  const float* x   = (const float*)d_in[1];
  auto cp = [&](int i) {
    return ConvP{ (const float*)d_in[i],     (const float*)d_in[i + 1],
                  (const float*)d_in[i + 2], (const float*)d_in[i + 3],
                  (const float*)d_in[i + 4], (const float*)d_in[i + 5],
                  (const float*)d_in[i + 6] };
  };
  ConvP fqk = cp(2), fv = cp(9), tqk = cp(16), pj = cp(23);

  char* ws = (char*)d_ws;
  const size_t SZ = (size_t)4 * 256 * 256 * 32 * 2;  // 16 MiB per bf16 buffer
  bf16* Qf = (bf16*)(ws + 0 * SZ);   // (B,F,T,CH)
  bf16* Kf = (bf16*)(ws + 1 * SZ);
  bf16* Vf = (bf16*)(ws + 2 * SZ);
  bf16* Qt = (bf16*)(ws + 3 * SZ);
  bf16* Kt = (bf16*)(ws + 4 * SZ);
  bf16* Ft = (bf16*)(ws + 5 * SZ);   // fout (B,F,T,CH)

  conv_qkv<<<1024, 256, 0, stream>>>(inp, x, fqk, fv, tqk, Qf, Kf, Vf, Qt, Kt);
  attn_k<false><<<1024, 256, 0, stream>>>(Qf, Kf, Vf, Ft);       // freq attention
  attn_proj<<<1024, 256, 0, stream>>>(Qt, Kt, Ft, pj, x, (float*)d_out);  // t-attn + proj fused
}